// Round 2
// baseline (347.477 us; speedup 1.0000x reference)
//
#include <hip/hip_runtime.h>
#include <hip/hip_bf16.h>

#define BATCH 4096

typedef __attribute__((ext_vector_type(8))) short short8;
typedef __attribute__((ext_vector_type(4))) short short4_t;
typedef __attribute__((ext_vector_type(4))) float f32x4;

#define MFMA_BF16 __builtin_amdgcn_mfma_f32_16x16x32_bf16

__device__ __forceinline__ float frelu(float v) { return v > 0.f ? v : 0.f; }
__device__ __forceinline__ unsigned short f2bf(float f) {
    return __builtin_bit_cast(unsigned short, __float2bfloat16(f));
}
__device__ __forceinline__ short8 cvt8(const float* p) {
    float4 a = *(const float4*)p;
    float4 b = *(const float4*)(p + 4);
    short8 r;
    r[0] = (short)f2bf(a.x); r[1] = (short)f2bf(a.y); r[2] = (short)f2bf(a.z); r[3] = (short)f2bf(a.w);
    r[4] = (short)f2bf(b.x); r[5] = (short)f2bf(b.y); r[6] = (short)f2bf(b.z); r[7] = (short)f2bf(b.w);
    return r;
}

// ---------------- prep: permute+cvt weights to bf16 K-contiguous layouts; init out ----------------
// w2p[oc][khw*32+ic], w3p[oc][khw*64+ic], w4p[n][pos*64+oc]; out[0..8191]=b5; ave tail zero.
__global__ __launch_bounds__(256) void prep_kernel(const float* __restrict__ w2, const float* __restrict__ w3,
                                                   const float* __restrict__ w4, const float* __restrict__ b5,
                                                   unsigned short* __restrict__ w2p, unsigned short* __restrict__ w3p,
                                                   unsigned short* __restrict__ w4p, float* __restrict__ out) {
    int idx = blockIdx.x * 256 + threadIdx.x;
    if (idx < 18432) {
        int oc = idx / 288, k = idx % 288;
        int khw = k / 32, ic = k % 32;
        w2p[idx] = f2bf(w2[oc * 288 + ic * 9 + khw]);
    } else if (idx < 55296) {
        int j = idx - 18432;
        int oc = j / 576, k = j % 576;
        int khw = k / 64, ic = k % 64;
        w3p[j] = f2bf(w3[oc * 576 + ic * 9 + khw]);
    } else if (idx < 546816) {
        int j = idx - 55296;
        int n = j / 960, k = j % 960;
        int pos = k / 64, oc = k % 64;
        w4p[j] = f2bf(w4[n * 960 + oc * 15 + pos]);
    } else if (idx < 555008) {
        int j = idx - 546816;
        out[j] = b5[j & 1];
    } else if (idx < 555223) {
        out[8192 + (idx - 555008)] = 0.f;
    }
}

// ---------------- fused conv1+conv2+conv3: one block per image, all intermediates in LDS ----------------
// x[B,3,48,64] -> (conv1) x2l LDS [165][36] -> (conv2) x4l LDS [35][72] -> (conv3) x6 global [B,960].
// ave partials -> redbuf rows: 0..164 = ave1-pos, 165..199 = ave2-pos, 200..214 = ave3-pos.
__global__ __launch_bounds__(256) void fused_convs(const float* __restrict__ x,
                                                   const float* __restrict__ w1, const float* __restrict__ b1,
                                                   const unsigned short* __restrict__ w2p, const float* __restrict__ b2,
                                                   const unsigned short* __restrict__ w3p, const float* __restrict__ b3,
                                                   unsigned short* __restrict__ x6, float* __restrict__ redbuf) {
    constexpr int RS = 68;                                   // input row stride (shorts)
    __shared__ __align__(16) unsigned short xl[3 * 48 * RS]; // 9792 shorts; dead after conv1, overlaid below
    __shared__ __align__(16) unsigned short x2l[165 * 36];   // 5940 shorts, conv1 out (pad 32->36)
    __shared__ float red1l[165];
    __shared__ float red2l[35];
    __shared__ float red3l[15];
    unsigned short* x4l = xl;                                // [35][72] = 2520 shorts (pad 64->72)
    unsigned short* x6l = xl + 2560;                         // [15][64] = 960 shorts (16B-aligned)

    const int img = blockIdx.x;
    const int tid = threadIdx.x;
    const int wave = tid >> 6, lane = tid & 63;
    const int col = lane & 15, quad = lane >> 4;

    if (tid < 165) red1l[tid] = 0.f;
    else if (tid < 200) red2l[tid - 165] = 0.f;
    else if (tid < 215) red3l[tid - 200] = 0.f;

    // stage image: 2304 float4 coalesced, convert once to bf16
    {
        const float4* xs = (const float4*)(x + (size_t)img * 9216);
        #pragma unroll
        for (int i = 0; i < 9; ++i) {
            const int idx = tid + i * 256;
            float4 v = xs[idx];
            const int fo = idx * 4;
            const int r = fo >> 6, cf = fo & 63;
            short4_t s;
            s[0] = (short)f2bf(v.x); s[1] = (short)f2bf(v.y);
            s[2] = (short)f2bf(v.z); s[3] = (short)f2bf(v.w);
            *(short4_t*)(xl + r * RS + cf) = s;
        }
    }

    // conv1 weight fragments (w1 tiny, L2-hot)
    short8 Bf1[2][6];
    #pragma unroll
    for (int nt = 0; nt < 2; ++nt) {
        const int oc = nt * 16 + col;
        #pragma unroll
        for (int c = 0; c < 6; ++c)
            Bf1[nt][c] = cvt8(w1 + oc * 192 + c * 32 + quad * 8);
    }
    const float bias0 = b1[col], bias1 = b1[col + 16];
    __syncthreads();

    // ---- conv1: 11 m-tiles over 4 waves, N=32 (2 n-tiles), K=192 (6 chunks) ----
    #pragma unroll
    for (int ti = 0; ti < 3; ++ti) {
        const int t = wave + ti * 4;
        if (t >= 11) break;
        const int posA = t * 16 + col;
        const int pm = posA < 165 ? posA : 164;
        const int oh = pm / 15, ow = pm % 15;
        f32x4 acc0 = {0.f, 0.f, 0.f, 0.f}, acc1 = {0.f, 0.f, 0.f, 0.f};
        #pragma unroll
        for (int c = 0; c < 6; ++c) {
            const int ic = c >> 1;
            const int kh = (c & 1) * 4 + quad;
            const unsigned short* ap = xl + (ic * 48 + oh * 4 + kh) * RS + ow * 4;
            short8 af;
            *(short4_t*)&af       = *(const short4_t*)ap;
            *((short4_t*)&af + 1) = *(const short4_t*)(ap + 4);
            acc0 = MFMA_BF16(af, Bf1[0][c], acc0, 0, 0, 0);
            acc1 = MFMA_BF16(af, Bf1[1][c], acc1, 0, 0, 0);
        }
        #pragma unroll
        for (int r = 0; r < 4; ++r) {
            const int pr = t * 16 + quad * 4 + r;
            float v0 = acc0[r] + bias0;
            float v1 = acc1[r] + bias1;
            float s = v0 + v1;
            s += __shfl_xor(s, 1); s += __shfl_xor(s, 2);
            s += __shfl_xor(s, 4); s += __shfl_xor(s, 8);
            if (pr < 165) {
                if (col == 0) atomicAdd(&red1l[pr], s);
                x2l[pr * 36 + col]      = f2bf(frelu(v0));
                x2l[pr * 36 + col + 16] = f2bf(frelu(v1));
            }
        }
    }
    __syncthreads();   // x2l complete; xl reads done -> x4l may overlay

    // ---- conv2: M=35 (3 m-tiles), each wave owns n-slice nt=wave (16 oc), K=288 (9 chunks) ----
    {
        const int oc2 = wave * 16 + col;
        short8 Bf2[9];
        #pragma unroll
        for (int c = 0; c < 9; ++c)
            Bf2[c] = *(const short8*)(w2p + (size_t)oc2 * 288 + c * 32 + quad * 8);
        const float bv2 = b2[oc2];

        int aoff[3];
        #pragma unroll
        for (int mt = 0; mt < 3; ++mt) {
            int p = mt * 16 + col; p = p < 35 ? p : 34;
            const int oh2 = p / 7, ow2 = p % 7;
            aoff[mt] = (oh2 * 30 + ow2 * 2) * 36 + quad * 8;
        }
        f32x4 acc[3] = {};
        #pragma unroll
        for (int c = 0; c < 9; ++c) {
            const int kh = c / 3, kw = c % 3;
            const int koff = (kh * 15 + kw) * 36;
            #pragma unroll
            for (int mt = 0; mt < 3; ++mt) {
                const unsigned short* ap = x2l + aoff[mt] + koff;
                short8 af;
                *(short4_t*)&af       = *(const short4_t*)ap;
                *((short4_t*)&af + 1) = *(const short4_t*)(ap + 4);
                acc[mt] = MFMA_BF16(af, Bf2[c], acc[mt], 0, 0, 0);
            }
        }
        #pragma unroll
        for (int mt = 0; mt < 3; ++mt) {
            #pragma unroll
            for (int r = 0; r < 4; ++r) {
                const int pr = mt * 16 + quad * 4 + r;
                float v = acc[mt][r] + bv2;
                float s = v;
                s += __shfl_xor(s, 1); s += __shfl_xor(s, 2);
                s += __shfl_xor(s, 4); s += __shfl_xor(s, 8);
                if (pr < 35) {
                    x4l[pr * 72 + oc2] = f2bf(frelu(v));
                    if (col == 0) atomicAdd(&red2l[pr], s);
                }
            }
        }
    }
    __syncthreads();

    // ---- conv3: M=15 (1 m-tile), wave owns n-slice nt=wave, K=576 (18 chunks) ----
    {
        const int oc3 = wave * 16 + col;
        short8 Bf3[18];
        #pragma unroll
        for (int c = 0; c < 18; ++c)
            Bf3[c] = *(const short8*)(w3p + (size_t)oc3 * 576 + c * 32 + quad * 8);
        const float bv3 = b3[oc3];

        int p = col < 15 ? col : 14;
        const int abase = ((p / 5) * 7 + (p % 5)) * 72;
        f32x4 acc = {};
        #pragma unroll
        for (int c = 0; c < 18; ++c) {
            const int khw = c >> 1, kh = khw / 3, kw = khw % 3;
            const unsigned short* ap = x4l + abase + (kh * 7 + kw) * 72 + (c & 1) * 32 + quad * 8;
            short8 af = *(const short8*)ap;          // 16B-aligned
            acc = MFMA_BF16(af, Bf3[c], acc, 0, 0, 0);
        }
        #pragma unroll
        for (int r = 0; r < 4; ++r) {
            const int pr = quad * 4 + r;
            float v = acc[r] + bv3;
            float s = v;
            s += __shfl_xor(s, 1); s += __shfl_xor(s, 2);
            s += __shfl_xor(s, 4); s += __shfl_xor(s, 8);
            if (pr < 15) {
                x6l[pr * 64 + oc3] = f2bf(frelu(v));
                if (col == 0) atomicAdd(&red3l[pr], s);
            }
        }
    }
    __syncthreads();

    // exports: coalesced x6 store + ave partials
    if (tid < 120) ((float4*)(x6 + (size_t)img * 960))[tid] = ((const float4*)x6l)[tid];
    if (tid < 215) {
        float v = tid < 165 ? red1l[tid] : (tid < 200 ? red2l[tid - 165] : red3l[tid - 200]);
        redbuf[(size_t)tid * 4096 + img] = v;
    }
}

// ---------------- reduce: out[8192+row] = sum_img redbuf[row][img] * scale ----------------
__global__ __launch_bounds__(256) void reduce_aves(const float* __restrict__ redbuf, float* __restrict__ out) {
    const int row = blockIdx.x;
    float s = 0.f;
    for (int i = threadIdx.x; i < 4096; i += 256) s += redbuf[(size_t)row * 4096 + i];
    s += __shfl_down(s, 32); s += __shfl_down(s, 16); s += __shfl_down(s, 8);
    s += __shfl_down(s, 4);  s += __shfl_down(s, 2);  s += __shfl_down(s, 1);
    __shared__ float wsum[4];
    if ((threadIdx.x & 63) == 0) wsum[threadIdx.x >> 6] = s;
    __syncthreads();
    if (threadIdx.x == 0)
        out[8192 + row] = (wsum[0] + wsum[1] + wsum[2] + wsum[3]) * (row < 165 ? 0.03125f : 0.015625f);
}

// ---------------- fc4+fc5: out[b,2] += relu(x6@w4p^T + b4) @ w5^T ----------------
// grid (128,8): 32 m-rows x 64 oc per block; wave owns n-slice nt=wave (16 oc) x 2 m-tiles, K=30 chunks.
__global__ __launch_bounds__(256) void fc45_mfma(const unsigned short* __restrict__ x6,
                                                 const unsigned short* __restrict__ w4p, const float* __restrict__ b4,
                                                 const float* __restrict__ w5, float* __restrict__ out) {
    __shared__ float outl[32][2];
    const int tid = threadIdx.x;
    const int wave = tid >> 6, lane = tid & 63;
    const int col = lane & 15, quad = lane >> 4;
    if (tid < 64) outl[tid >> 1][tid & 1] = 0.f;
    const int m0 = blockIdx.x * 32;
    const int oc = blockIdx.y * 64 + wave * 16 + col;

    const unsigned short* brow  = w4p + (size_t)oc * 960 + quad * 8;
    const unsigned short* arow0 = x6 + (size_t)(m0 + col) * 960 + quad * 8;
    const unsigned short* arow1 = arow0 + 16 * 960;
    f32x4 acc0 = {}, acc1 = {};
    __syncthreads();
    #pragma unroll 6
    for (int c = 0; c < 30; ++c) {
        short8 Bf = *(const short8*)(brow + c * 32);
        short8 a0 = *(const short8*)(arow0 + c * 32);
        short8 a1 = *(const short8*)(arow1 + c * 32);
        acc0 = MFMA_BF16(a0, Bf, acc0, 0, 0, 0);
        acc1 = MFMA_BF16(a1, Bf, acc1, 0, 0, 0);
    }
    const float bb = b4[oc], u0 = w5[oc], u1 = w5[512 + oc];
    #pragma unroll
    for (int mi = 0; mi < 2; ++mi) {
        const f32x4 acc = mi ? acc1 : acc0;
        #pragma unroll
        for (int r = 0; r < 4; ++r) {
            float h = frelu(acc[r] + bb);
            float l0 = h * u0, l1 = h * u1;
            l0 += __shfl_xor(l0, 1); l0 += __shfl_xor(l0, 2); l0 += __shfl_xor(l0, 4); l0 += __shfl_xor(l0, 8);
            l1 += __shfl_xor(l1, 1); l1 += __shfl_xor(l1, 2); l1 += __shfl_xor(l1, 4); l1 += __shfl_xor(l1, 8);
            if (col == 0) {
                atomicAdd(&outl[mi * 16 + quad * 4 + r][0], l0);
                atomicAdd(&outl[mi * 16 + quad * 4 + r][1], l1);
            }
        }
    }
    __syncthreads();
    if (tid < 64) atomicAdd(&out[(m0 + (tid >> 1)) * 2 + (tid & 1)], outl[tid >> 1][tid & 1]);
}

extern "C" void kernel_launch(void* const* d_in, const int* in_sizes, int n_in,
                              void* d_out, int out_size, void* d_ws, size_t ws_size,
                              hipStream_t stream) {
    const float* x  = (const float*)d_in[0];
    const float* w1 = (const float*)d_in[1];
    const float* b1 = (const float*)d_in[2];
    const float* w2 = (const float*)d_in[3];
    const float* b2 = (const float*)d_in[4];
    const float* w3 = (const float*)d_in[5];
    const float* b3 = (const float*)d_in[6];
    const float* w4 = (const float*)d_in[7];
    const float* b4 = (const float*)d_in[8];
    const float* w5 = (const float*)d_in[9];
    const float* b5 = (const float*)d_in[10];
    float* out = (float*)d_out;

    unsigned short* ws = (unsigned short*)d_ws;
    unsigned short* x6  = ws;                      // 3,932,160 ushort
    unsigned short* w2p = ws + 3932160;            //     18,432
    unsigned short* w3p = ws + 3950592;            //     36,864
    unsigned short* w4p = ws + 3987456;            //    491,520
    float* redbuf = (float*)((char*)d_ws + 8957952); // 215*4096 floats

    prep_kernel<<<2169, 256, 0, stream>>>(w2, w3, w4, b5, w2p, w3p, w4p, out);
    fused_convs<<<BATCH, 256, 0, stream>>>(x, w1, b1, w2p, b2, w3p, b3, x6, redbuf);
    reduce_aves<<<215, 256, 0, stream>>>(redbuf, out);
    fc45_mfma<<<dim3(128, 8), 256, 0, stream>>>(x6, w4p, b4, w5, out);
}